// Round 7
// baseline (324.214 us; speedup 1.0000x reference)
//
#include <hip/hip_runtime.h>
#include <hip/hip_bf16.h>

#define HID 96
#define NGRAPHS 64
#define SENT 0xC3C3u   // 50115: sentinel row (zeroed) for CSR padding
#define NROWS 50116    // N + sentinel row
#define PLN48 ((size_t)NROWS * 48)   // bytes per fp8 48-feature plane

typedef __attribute__((ext_vector_type(8))) short short8;
typedef __attribute__((ext_vector_type(4))) float floatx4;
typedef __attribute__((ext_vector_type(2))) float floatx2;
typedef __attribute__((ext_vector_type(8))) unsigned short ushort8v;
typedef __attribute__((ext_vector_type(2))) unsigned int uint2v;

__device__ __forceinline__ unsigned short f32_to_bf16(float f) {
    unsigned int u = __builtin_bit_cast(unsigned int, f);
    u += 0x7fff + ((u >> 16) & 1);  // RNE
    return (unsigned short)(u >> 16);
}
// Single f32 -> fp8 e4m3 byte (HW cvt; byte0 of the packed result).
__device__ __forceinline__ unsigned char f32_to_fp8(float f) {
    return (unsigned char)(__builtin_amdgcn_cvt_pk_fp8_f32(f, f, 0, false) & 0xff);
}
// Decode one fp8x8 fragment into f32[8].
__device__ __forceinline__ void fp8x8_decode(uint2v u, float* __restrict__ o) {
    floatx2 a0 = __builtin_amdgcn_cvt_pk_f32_fp8(u[0], false);
    floatx2 a1 = __builtin_amdgcn_cvt_pk_f32_fp8(u[0], true);
    floatx2 a2 = __builtin_amdgcn_cvt_pk_f32_fp8(u[1], false);
    floatx2 a3 = __builtin_amdgcn_cvt_pk_f32_fp8(u[1], true);
    o[0] = a0[0]; o[1] = a0[1]; o[2] = a1[0]; o[3] = a1[1];
    o[4] = a2[0]; o[5] = a2[1]; o[6] = a3[0]; o[7] = a3[1];
}

// ---------------------------------------------------------------------------
// fp8 wide-gather core, PAD-4 rows, templated row stride (96 = interleaved
// full row; 48 = one feature plane). Wave = 4 groups x 16 lanes; active lanes
// load 8 features (uint2v, 8B) of one edge-row. Each group owns 2 consecutive
// CSR rows [r0,r2) with boundary r1, all multiples of 4. Slots processed in
// 4-slot halves; per-half predicates route into aA / aB / discard.
// ---------------------------------------------------------------------------
template <int RS>
__device__ __forceinline__ void gather_core4(
    const unsigned char* __restrict__ h8, const unsigned short* __restrict__ csr,
    int r0, int r1, int r2, int TAIL, int it2, int pe8,
    float* __restrict__ aA, float* __restrict__ aB) {
    int s = r0;
    ushort8v i0 = *(const ushort8v*)(csr + (s < r2 ? s : TAIL));
    ushort8v i1 = *(const ushort8v*)(csr + (s + 8 < r2 ? s + 8 : TAIL));
    for (int it = 0; it < it2; ++it) {
        uint2v v0[8], v1[8];
#pragma unroll
        for (int j = 0; j < 8; ++j)
            v0[j] = *(const uint2v*)(h8 + (int)i0[j] * RS + pe8);
#pragma unroll
        for (int j = 0; j < 8; ++j)
            v1[j] = *(const uint2v*)(h8 + (int)i1[j] * RS + pe8);
        int sn = s + 16;
        ushort8v n0 = *(const ushort8v*)(csr + (sn < r2 ? sn : TAIL));
        ushort8v n1 = *(const ushort8v*)(csr + (sn + 8 < r2 ? sn + 8 : TAIL));
        // 4 halves at bases s, s+4, s+8, s+12: sum 4 rows, then route.
#pragma unroll
        for (int h = 0; h < 4; ++h) {
            float t[8] = {0, 0, 0, 0, 0, 0, 0, 0};
#pragma unroll
            for (int j = 0; j < 4; ++j) {
                float d[8];
                fp8x8_decode((h < 2 ? v0 : v1)[(h & 1) * 4 + j], d);
#pragma unroll
                for (int f = 0; f < 8; ++f) t[f] += d[f];
            }
            int bh = s + h * 4;
            bool bA = bh < r1;   // half fully in row A (4-aligned bounds)
            bool bV = bh < r2;   // half within this group's range at all
#pragma unroll
            for (int f = 0; f < 8; ++f) {
                float x = bA ? t[f] : 0.0f;
                float v = bV ? t[f] : 0.0f;
                aA[f] += x;
                aB[f] += v - x;
            }
        }
        i0 = n0;
        i1 = n1;
        s = sn;
    }
}

// ------------------------------------------------------ init + weight prep --
// Blocks [0,NB): zero deg/psum/sentinel rows. Blocks [NB,NB+3): swizzle W.
__global__ __launch_bounds__(256) void init_kernel(
    int* __restrict__ deg, float* __restrict__ psum,
    unsigned char* __restrict__ bufA, unsigned char* __restrict__ bufB,
    unsigned char* __restrict__ bufP, int N,
    int NB, const float* __restrict__ W0, const float* __restrict__ W1,
    const float* __restrict__ W2, unsigned short* __restrict__ Wz) {
    int b = blockIdx.x;
    if (b >= NB) {
        int wsel = b - NB;
        const float* W = (wsel == 0) ? W0 : (wsel == 1) ? W1 : W2;
        unsigned short* dst = Wz + wsel * HID * HID;
        for (int e = threadIdx.x; e < HID * HID; e += blockDim.x) {
            int k = e / HID, n = e % HID;
            int nt = n >> 4, kki = k >> 5, quad = (k >> 3) & 3, j = k & 7;
            int lane = (n & 15) | (quad << 4);
            dst[(((nt * 3 + kki) * 64 + lane) << 3) | j] = f32_to_bf16(W[e]);
        }
        return;
    }
    int i = b * 256 + threadIdx.x;
    if (i < N) deg[i] = 0;
    if (i < NGRAPHS * HID + NGRAPHS) psum[i] = 0.0f;
    if (i < HID) {
        bufA[(size_t)SENT * HID + i] = 0;  // fp8 0x00 == 0.0
        bufB[(size_t)SENT * HID + i] = 0;
    }
    if (i < 48) {
        bufP[(size_t)SENT * 48 + i] = 0;          // plane 0 sentinel
        bufP[PLN48 + (size_t)SENT * 48 + i] = 0;  // plane 1 sentinel
    }
}

// ---------------------------------------------------------------- degree ----
__global__ void deg_kernel(const int* __restrict__ dst, int* __restrict__ deg,
                           int n_edges) {
    int t = blockIdx.x * blockDim.x + threadIdx.x;
    int e0 = t * 4;
    if (e0 + 4 <= n_edges) {
        int4 d4 = *(const int4*)(dst + e0);
        atomicAdd(&deg[d4.x], 1);
        atomicAdd(&deg[d4.y], 1);
        atomicAdd(&deg[d4.z], 1);
        atomicAdd(&deg[d4.w], 1);
    } else {
        for (int e = e0; e < n_edges; e++) atomicAdd(&deg[dst[e]], 1);
    }
}

// ------------------------------------------- scan (padded to 4) + dinv ------
__global__ __launch_bounds__(256) void scan_phaseA(const int* __restrict__ deg,
                                                   float* __restrict__ dinv,
                                                   int* __restrict__ blocksum,
                                                   int N) {
    int i = blockIdx.x * 256 + threadIdx.x;
    int d = (i < N) ? deg[i] : 0;
    if (i < N) dinv[i] = rsqrtf((float)d + 1.0f);
    int v = (d + 3) & ~3;  // padded degree (pad-4)
#pragma unroll
    for (int off = 32; off > 0; off >>= 1) v += __shfl_down(v, off, 64);
    __shared__ int s[4];
    if ((threadIdx.x & 63) == 0) s[threadIdx.x >> 6] = v;
    __syncthreads();
    if (threadIdx.x == 0) blocksum[blockIdx.x] = s[0] + s[1] + s[2] + s[3];
}

__global__ __launch_bounds__(256) void scan_phaseC(const int* __restrict__ deg,
                                                   const int* __restrict__ blocksum,
                                                   int* __restrict__ rowptr,
                                                   int* __restrict__ cursor,
                                                   int N, int NB) {
    int t = threadIdx.x;
    int mine = (t < NB && t < blockIdx.x) ? blocksum[t] : 0;
#pragma unroll
    for (int off = 32; off > 0; off >>= 1) mine += __shfl_down(mine, off, 64);
    __shared__ int ps[4];
    if ((t & 63) == 0) ps[t >> 6] = mine;
    __syncthreads();
    int pref = ps[0] + ps[1] + ps[2] + ps[3];

    __shared__ int s[256];
    int i = blockIdx.x * 256 + t;
    int own = (i < N) ? (deg[i] + 3) & ~3 : 0;  // pad-4
    s[t] = own;
    __syncthreads();
#pragma unroll
    for (int off = 1; off < 256; off <<= 1) {
        int v = (t >= off) ? s[t - off] : 0;
        __syncthreads();
        s[t] += v;
        __syncthreads();
    }
    if (i < N) {
        int r = pref + s[t] - own;
        rowptr[i] = r;
        cursor[i] = r;
        if (i == N - 1) rowptr[N] = r + own;
    }
}

// ------------------------------------------------------------------ fill ----
__global__ void csr_fill(const int* __restrict__ src, const int* __restrict__ dst,
                         int* __restrict__ cursor,
                         unsigned short* __restrict__ csr_src, int n_edges) {
    int t = blockIdx.x * blockDim.x + threadIdx.x;
    int e0 = t * 8;
    if (e0 + 8 <= n_edges) {
        int4 da = *(const int4*)(dst + e0);
        int4 db = *(const int4*)(dst + e0 + 4);
        int4 sa = *(const int4*)(src + e0);
        int4 sb = *(const int4*)(src + e0 + 4);
        int p0 = atomicAdd(&cursor[da.x], 1);
        int p1 = atomicAdd(&cursor[da.y], 1);
        int p2 = atomicAdd(&cursor[da.z], 1);
        int p3 = atomicAdd(&cursor[da.w], 1);
        int p4 = atomicAdd(&cursor[db.x], 1);
        int p5 = atomicAdd(&cursor[db.y], 1);
        int p6 = atomicAdd(&cursor[db.z], 1);
        int p7 = atomicAdd(&cursor[db.w], 1);
        csr_src[p0] = (unsigned short)sa.x;
        csr_src[p1] = (unsigned short)sa.y;
        csr_src[p2] = (unsigned short)sa.z;
        csr_src[p3] = (unsigned short)sa.w;
        csr_src[p4] = (unsigned short)sb.x;
        csr_src[p5] = (unsigned short)sb.y;
        csr_src[p6] = (unsigned short)sb.z;
        csr_src[p7] = (unsigned short)sb.w;
    } else {
        for (int e = e0; e < n_edges; e++) {
            int p = atomicAdd(&cursor[dst[e]], 1);
            csr_src[p] = (unsigned short)src[e];
        }
    }
}

// ----------------------------------------------------- GEMM0 (f32 input) ----
__global__ __launch_bounds__(256) void gemm0_f32(
    const float* __restrict__ X, const unsigned short* __restrict__ Wz,
    const float* __restrict__ dinv, unsigned char* __restrict__ Out, int Mtiles) {
    int wv = threadIdx.x >> 6;
    int lane = threadIdx.x & 63;
    int quad = lane >> 4;
    int mrow = lane & 15;
    int tt = blockIdx.x * 2 + (wv >> 1);
    int half = wv & 1;
    if (tt >= Mtiles) return;

    short8 bfrag[9];
    const short8* Wz8 = (const short8*)Wz;
#pragma unroll
    for (int f = 0; f < 9; f++) bfrag[f] = Wz8[(half * 9 + f) * 64 + lane];

    int m0 = tt * 16;
    const float* arow = X + (size_t)(m0 + mrow) * HID + quad * 8;
    short8 a[3];
#pragma unroll
    for (int kb = 0; kb < 3; kb++) {
        float4 u = *(const float4*)(arow + kb * 32);
        float4 v = *(const float4*)(arow + kb * 32 + 4);
        short8 t;
        t[0] = (short)f32_to_bf16(u.x); t[1] = (short)f32_to_bf16(u.y);
        t[2] = (short)f32_to_bf16(u.z); t[3] = (short)f32_to_bf16(u.w);
        t[4] = (short)f32_to_bf16(v.x); t[5] = (short)f32_to_bf16(v.y);
        t[6] = (short)f32_to_bf16(v.z); t[7] = (short)f32_to_bf16(v.w);
        a[kb] = t;
    }
    float dscale[4];
#pragma unroll
    for (int r = 0; r < 4; r++) dscale[r] = dinv[m0 + quad * 4 + r];
    unsigned char* orow = Out + (size_t)m0 * HID;
#pragma unroll
    for (int ntl = 0; ntl < 3; ntl++) {
        int nt = half * 3 + ntl;
        floatx4 c = {0.0f, 0.0f, 0.0f, 0.0f};
        c = __builtin_amdgcn_mfma_f32_16x16x32_bf16(a[0], bfrag[ntl * 3 + 0], c, 0, 0, 0);
        c = __builtin_amdgcn_mfma_f32_16x16x32_bf16(a[1], bfrag[ntl * 3 + 1], c, 0, 0, 0);
        c = __builtin_amdgcn_mfma_f32_16x16x32_bf16(a[2], bfrag[ntl * 3 + 2], c, 0, 0, 0);
#pragma unroll
        for (int r = 0; r < 4; r++)
            orow[(size_t)(quad * 4 + r) * HID + nt * 16 + mrow] =
                f32_to_fp8(c[r] * dscale[r]);
    }
}

// ------------------------------------------------ fused gather + GEMM -------
// Gather reads interleaved fp8 (RS=96, control arm). Epilogue writes either
// interleaved (planar=0) or the two 48-feature planes of OutP (planar=1).
__global__ __launch_bounds__(256) void fused_gather_gemm(
    const unsigned char* __restrict__ h8, const int* __restrict__ rowptr,
    const unsigned short* __restrict__ csr, const float* __restrict__ dinv,
    const float* __restrict__ bias, const unsigned short* __restrict__ Wz,
    unsigned char* __restrict__ Out, int Mtiles, int N, int planar) {
    __shared__ unsigned short tile[2][16][104];  // stride 104
    int wv = threadIdx.x >> 6;
    int lane = threadIdx.x & 63;
    int quad = lane >> 4;
    int mrow = lane & 15;
    int tsel = wv >> 1;
    int half = wv & 1;
    int tt = blockIdx.x * 2 + tsel;
    bool active = tt < Mtiles;
    int g = lane >> 4;
    int p = lane & 15;
    int pe = (p < 12) ? p : 11;
    int pe8 = pe * 8;

    if (active) {
        int TAIL = rowptr[N];
        int j0 = half * 8 + g * 2;
        int na = tt * 16 + j0;
        int r0 = rowptr[na], r1 = rowptr[na + 1], r2 = rowptr[na + 2];
        float da = dinv[na], db = dinv[na + 1];
        float aA[8], aB[8];
        uint2v sva = *(const uint2v*)(h8 + (size_t)na * HID + pe8);
        uint2v svb = *(const uint2v*)(h8 + (size_t)(na + 1) * HID + pe8);
        fp8x8_decode(sva, aA);
        fp8x8_decode(svb, aB);
        int it2 = (r2 - r0 + 15) >> 4;
        int o = __shfl_xor(it2, 16, 64);
        it2 = it2 > o ? it2 : o;
        o = __shfl_xor(it2, 32, 64);
        it2 = it2 > o ? it2 : o;
        gather_core4<HID>(h8, csr, r0, r1, r2, TAIL, it2, pe8, aA, aB);
        float4 bb0 = *(const float4*)(bias + pe8);
        float4 bb1 = *(const float4*)(bias + pe8 + 4);
        float bv[8] = {bb0.x, bb0.y, bb0.z, bb0.w, bb1.x, bb1.y, bb1.z, bb1.w};
        if (p < 12) {
            ushort8v oA, oB;
#pragma unroll
            for (int f = 0; f < 8; ++f) {
                oA[f] = f32_to_bf16(fmaxf(aA[f] * da + bv[f], 0.0f));
                oB[f] = f32_to_bf16(fmaxf(aB[f] * db + bv[f], 0.0f));
            }
            *(ushort8v*)(&tile[tsel][j0][pe8]) = oA;
            *(ushort8v*)(&tile[tsel][j0 + 1][pe8]) = oB;
        }
    }
    __syncthreads();
    if (!active) return;

    short8 bfrag[9];
    const short8* Wz8 = (const short8*)Wz;
#pragma unroll
    for (int f = 0; f < 9; f++) bfrag[f] = Wz8[(half * 9 + f) * 64 + lane];

    const unsigned short* tp = &tile[tsel][0][0];
    short8 a[3];
#pragma unroll
    for (int kb = 0; kb < 3; kb++)
        a[kb] = *(const short8*)(tp + mrow * 104 + quad * 8 + kb * 32);
    int n0 = tt * 16;
    float dscale[4];
#pragma unroll
    for (int r = 0; r < 4; r++) dscale[r] = dinv[n0 + quad * 4 + r];
    if (planar) {
        // plane = half; plane-col = ntl*16 + mrow; row stride 48
        unsigned char* op = Out + (size_t)half * PLN48 + (size_t)n0 * 48;
#pragma unroll
        for (int ntl = 0; ntl < 3; ntl++) {
            floatx4 c = {0.0f, 0.0f, 0.0f, 0.0f};
            c = __builtin_amdgcn_mfma_f32_16x16x32_bf16(a[0], bfrag[ntl * 3 + 0], c, 0, 0, 0);
            c = __builtin_amdgcn_mfma_f32_16x16x32_bf16(a[1], bfrag[ntl * 3 + 1], c, 0, 0, 0);
            c = __builtin_amdgcn_mfma_f32_16x16x32_bf16(a[2], bfrag[ntl * 3 + 2], c, 0, 0, 0);
#pragma unroll
            for (int r = 0; r < 4; r++)
                op[(size_t)(quad * 4 + r) * 48 + ntl * 16 + mrow] =
                    f32_to_fp8(c[r] * dscale[r]);
        }
    } else {
        unsigned char* orow = Out + (size_t)n0 * HID;
#pragma unroll
        for (int ntl = 0; ntl < 3; ntl++) {
            int nt = half * 3 + ntl;
            floatx4 c = {0.0f, 0.0f, 0.0f, 0.0f};
            c = __builtin_amdgcn_mfma_f32_16x16x32_bf16(a[0], bfrag[ntl * 3 + 0], c, 0, 0, 0);
            c = __builtin_amdgcn_mfma_f32_16x16x32_bf16(a[1], bfrag[ntl * 3 + 1], c, 0, 0, 0);
            c = __builtin_amdgcn_mfma_f32_16x16x32_bf16(a[2], bfrag[ntl * 3 + 2], c, 0, 0, 0);
#pragma unroll
            for (int r = 0; r < 4; r++)
                orow[(size_t)(quad * 4 + r) * HID + nt * 16 + mrow] =
                    f32_to_fp8(c[r] * dscale[r]);
        }
    }
}

// --------------------------------------------- fused gather + pool, 1 plane -
// TEST ARM: one 2.4 MB feature plane per LAUNCH (hard L2-residency boundary).
// Gathers 48 features (RS=48, lanes p<6 active), stages f32 in per-wave LDS,
// then run-length pool into psum[g*96 + ph*48 + 0..47]. pcnt only in ph 0.
__global__ __launch_bounds__(256) void gather_pool_ph(
    const unsigned char* __restrict__ hp, const int* __restrict__ rowptr,
    const unsigned short* __restrict__ csr, const float* __restrict__ dinv,
    const float* __restrict__ bias, const int* __restrict__ batch,
    float* __restrict__ psum, float* __restrict__ pcnt, int Ntiles8, int N,
    int ph) {
    __shared__ float stage[4][8][48];  // 6 KB, per-wave region
    int wv = threadIdx.x >> 6;
    int lane = threadIdx.x & 63;
    int tt = blockIdx.x * 4 + wv;
    if (tt >= Ntiles8) return;
    int g = lane >> 4;
    int p = lane & 15;
    int pe = (p < 6) ? p : 5;
    int pe8 = pe * 8;

    int TAIL = rowptr[N];
    int n0 = tt * 8;
    int na = n0 + g * 2;
    int r0 = rowptr[na], r1 = rowptr[na + 1], r2 = rowptr[na + 2];
    float da = dinv[na], db = dinv[na + 1];
    float aA[8], aB[8];
    uint2v sva = *(const uint2v*)(hp + (size_t)na * 48 + pe8);
    uint2v svb = *(const uint2v*)(hp + (size_t)(na + 1) * 48 + pe8);
    fp8x8_decode(sva, aA);
    fp8x8_decode(svb, aB);
    int it2 = (r2 - r0 + 15) >> 4;
    int o = __shfl_xor(it2, 16, 64);
    it2 = it2 > o ? it2 : o;
    o = __shfl_xor(it2, 32, 64);
    it2 = it2 > o ? it2 : o;
    gather_core4<48>(hp, csr, r0, r1, r2, TAIL, it2, pe8, aA, aB);
    const float* bp = bias + ph * 48 + pe8;
    float4 bb0 = *(const float4*)(bp);
    float4 bb1 = *(const float4*)(bp + 4);
    float bv[8] = {bb0.x, bb0.y, bb0.z, bb0.w, bb1.x, bb1.y, bb1.z, bb1.w};
    if (p < 6) {  // last layer: no ReLU; single writer per fragment
        floatx4 oa0 = {aA[0] * da + bv[0], aA[1] * da + bv[1],
                       aA[2] * da + bv[2], aA[3] * da + bv[3]};
        floatx4 oa1 = {aA[4] * da + bv[4], aA[5] * da + bv[5],
                       aA[6] * da + bv[6], aA[7] * da + bv[7]};
        floatx4 ob0 = {aB[0] * db + bv[0], aB[1] * db + bv[1],
                       aB[2] * db + bv[2], aB[3] * db + bv[3]};
        floatx4 ob1 = {aB[4] * db + bv[4], aB[5] * db + bv[5],
                       aB[6] * db + bv[6], aB[7] * db + bv[7]};
        *(floatx4*)(&stage[wv][g * 2][pe8]) = oa0;
        *(floatx4*)(&stage[wv][g * 2][pe8 + 4]) = oa1;
        *(floatx4*)(&stage[wv][g * 2 + 1][pe8]) = ob0;
        *(floatx4*)(&stage[wv][g * 2 + 1][pe8 + 4]) = ob1;
    }
    asm volatile("s_waitcnt lgkmcnt(0)" ::: "memory");  // wave-local LDS fence

    int fi = (lane < 24) ? lane * 2 : 46;
    float* pbase = psum + ph * 48;
    int g_cur = batch[n0];
    float s0 = 0.0f, s1 = 0.0f;
    int cnt = 0;
#pragma unroll
    for (int j = 0; j < 8; ++j) {
        int gb = batch[n0 + j];
        if (gb != g_cur) {
            if (lane < 24) {
                atomicAdd(&pbase[g_cur * HID + fi], s0);
                atomicAdd(&pbase[g_cur * HID + fi + 1], s1);
            }
            if (ph == 0 && lane == 0) atomicAdd(&pcnt[g_cur], (float)cnt);
            s0 = 0.0f; s1 = 0.0f; cnt = 0;
            g_cur = gb;
        }
        s0 += stage[wv][j][fi];
        s1 += stage[wv][j][fi + 1];
        cnt++;
    }
    if (lane < 24) {
        atomicAdd(&pbase[g_cur * HID + fi], s0);
        atomicAdd(&pbase[g_cur * HID + fi + 1], s1);
    }
    if (ph == 0 && lane == 0) atomicAdd(&pcnt[g_cur], (float)cnt);
}

// ---------------------------------------------------------------- head ------
__global__ __launch_bounds__(640) void final_kernel(
    const float* __restrict__ sums, const float* __restrict__ cnts,
    const float* __restrict__ Wlin, const float* __restrict__ blin,
    float* __restrict__ out) {
    int t = threadIdx.x;
    if (t >= NGRAPHS * 10) return;
    int g = t / 10;
    int c = t % 10;
    float denom = fmaxf(cnts[g], 1.0f);
    float acc = blin[c];
#pragma unroll
    for (int f = 0; f < HID; f++)
        acc += (sums[g * HID + f] / denom) * Wlin[f * 10 + c];
    out[t] = acc;
}

// ---------------------------------------------------------------- launch ----
extern "C" void kernel_launch(void* const* d_in, const int* in_sizes, int n_in,
                              void* d_out, int out_size, void* d_ws,
                              size_t ws_size, hipStream_t stream) {
    const float* x = (const float*)d_in[0];
    const int* edge = (const int*)d_in[1];
    const int* batch = (const int*)d_in[2];
    const float* W[3] = {(const float*)d_in[3], (const float*)d_in[5],
                         (const float*)d_in[7]};
    const float* B[3] = {(const float*)d_in[4], (const float*)d_in[6],
                         (const float*)d_in[8]};
    const float* Wlin = (const float*)d_in[9];
    const float* blin = (const float*)d_in[10];
    float* out = (float*)d_out;

    int N = in_sizes[0] / HID;  // 50000
    int E = in_sizes[1] / 2;    // 800000
    const int* src = edge;
    const int* dst = edge + E;
    int NB = (N + 255) / 256;   // 196

    char* ws = (char*)d_ws;
    size_t off = 0;
    auto alloc = [&](size_t bytes) {
        void* p = ws + off;
        off += (bytes + 255) & ~(size_t)255;
        return p;
    };
    int* deg = (int*)alloc((size_t)N * 4);
    float* dinv = (float*)alloc((size_t)N * 4);
    int* rowptr = (int*)alloc(((size_t)N + 1) * 4);
    int* cursor = (int*)alloc((size_t)N * 4);
    int* blocksum = (int*)alloc((size_t)NB * 4);
    size_t csr_cap = (size_t)E + 4 * (size_t)N;  // pad-4
    unsigned short* csr_src = (unsigned short*)alloc(csr_cap * 2 + 64);
    unsigned short* Wz = (unsigned short*)alloc(3 * HID * HID * 2);
    unsigned char* bufA = (unsigned char*)alloc((size_t)NROWS * HID);  // fp8
    unsigned char* bufB = (unsigned char*)alloc((size_t)NROWS * HID);  // fp8
    unsigned char* bufP = (unsigned char*)alloc(2 * PLN48);  // planar fp8
    float* psum = (float*)alloc((NGRAPHS * HID + NGRAPHS) * 4);
    float* pcnt = psum + NGRAPHS * HID;

    // --- CSR build + weight prep ---
    hipMemsetAsync(csr_src, 0xC3, csr_cap * 2, stream);  // pads -> sentinel row
    init_kernel<<<NB + 3, 256, 0, stream>>>(deg, psum, bufA, bufB, bufP, N, NB,
                                            W[0], W[1], W[2], Wz);
    deg_kernel<<<(E / 4 + 255) / 256, 256, 0, stream>>>(dst, deg, E);
    scan_phaseA<<<NB, 256, 0, stream>>>(deg, dinv, blocksum, N);
    scan_phaseC<<<NB, 256, 0, stream>>>(deg, blocksum, rowptr, cursor, N, NB);
    csr_fill<<<(E / 8 + 255) / 256, 256, 0, stream>>>(src, dst, cursor, csr_src, E);

    int Mtiles = (N + 15) / 16;           // 3125
    int grid2 = (Mtiles + 1) / 2;         // 1563 (2 tiles/block)
    int Ntiles8 = (N + 7) / 8;            // 6250
    int gridp = (Ntiles8 + 3) / 4;        // 1563

    gemm0_f32<<<grid2, 256, 0, stream>>>(x, Wz, dinv, bufA, Mtiles);
    fused_gather_gemm<<<grid2, 256, 0, stream>>>(
        bufA, rowptr, csr_src, dinv, B[0], Wz + 1 * HID * HID, bufB, Mtiles, N, 0);
    fused_gather_gemm<<<grid2, 256, 0, stream>>>(
        bufB, rowptr, csr_src, dinv, B[1], Wz + 2 * HID * HID, bufP, Mtiles, N, 1);
    gather_pool_ph<<<gridp, 256, 0, stream>>>(bufP, rowptr, csr_src, dinv, B[2],
                                              batch, psum, pcnt, Ntiles8, N, 0);
    gather_pool_ph<<<gridp, 256, 0, stream>>>(bufP + PLN48, rowptr, csr_src, dinv,
                                              B[2], batch, psum, pcnt, Ntiles8, N, 1);
    final_kernel<<<1, 640, 0, stream>>>(psum, pcnt, Wlin, blin, out);
}

// Round 8
// 272.524 us; speedup vs baseline: 1.1897x; 1.1897x over previous
//
#include <hip/hip_runtime.h>
#include <hip/hip_bf16.h>

#define HID 96
#define NGRAPHS 64
#define SENT 0xC3C3u   // 50115: sentinel row (zeroed) for CSR padding
#define NROWS 50116    // N + sentinel row

typedef __attribute__((ext_vector_type(8))) short short8;
typedef __attribute__((ext_vector_type(4))) float floatx4;
typedef __attribute__((ext_vector_type(2))) float floatx2;
typedef __attribute__((ext_vector_type(8))) unsigned short ushort8v;
typedef __attribute__((ext_vector_type(2))) unsigned int uint2v;

__device__ __forceinline__ unsigned short f32_to_bf16(float f) {
    unsigned int u = __builtin_bit_cast(unsigned int, f);
    u += 0x7fff + ((u >> 16) & 1);  // RNE
    return (unsigned short)(u >> 16);
}
// Single f32 -> fp8 e4m3 byte (HW cvt; byte0 of the packed result).
__device__ __forceinline__ unsigned char f32_to_fp8(float f) {
    return (unsigned char)(__builtin_amdgcn_cvt_pk_fp8_f32(f, f, 0, false) & 0xff);
}
// Decode one fp8x8 fragment into f32[8].
__device__ __forceinline__ void fp8x8_decode(uint2v u, float* __restrict__ o) {
    floatx2 a0 = __builtin_amdgcn_cvt_pk_f32_fp8(u[0], false);
    floatx2 a1 = __builtin_amdgcn_cvt_pk_f32_fp8(u[0], true);
    floatx2 a2 = __builtin_amdgcn_cvt_pk_f32_fp8(u[1], false);
    floatx2 a3 = __builtin_amdgcn_cvt_pk_f32_fp8(u[1], true);
    o[0] = a0[0]; o[1] = a0[1]; o[2] = a1[0]; o[3] = a1[1];
    o[4] = a2[0]; o[5] = a2[1]; o[6] = a3[0]; o[7] = a3[1];
}

// ---------------------------------------------------------------------------
// fp8 wide-gather core, PAD-4 rows. Wave = 4 groups x 16 lanes; lane p<12
// loads 8 features (uint2v, 8B) of one edge-row (96B row). Each group owns 2
// consecutive CSR rows [r0,r2) with boundary r1, all multiples of 4.
// Slots processed in 4-slot halves; per-half predicates route into aA/aB or
// discard (slot >= r2). Index vectors prefetched one iteration ahead.
// ---------------------------------------------------------------------------
__device__ __forceinline__ void gather_core4(
    const unsigned char* __restrict__ h8, const unsigned short* __restrict__ csr,
    int r0, int r1, int r2, int TAIL, int it2, int pe8,
    float* __restrict__ aA, float* __restrict__ aB) {
    int s = r0;
    ushort8v i0 = *(const ushort8v*)(csr + (s < r2 ? s : TAIL));
    ushort8v i1 = *(const ushort8v*)(csr + (s + 8 < r2 ? s + 8 : TAIL));
    for (int it = 0; it < it2; ++it) {
        uint2v v0[8], v1[8];
#pragma unroll
        for (int j = 0; j < 8; ++j)
            v0[j] = *(const uint2v*)(h8 + (int)i0[j] * HID + pe8);
#pragma unroll
        for (int j = 0; j < 8; ++j)
            v1[j] = *(const uint2v*)(h8 + (int)i1[j] * HID + pe8);
        int sn = s + 16;
        ushort8v n0 = *(const ushort8v*)(csr + (sn < r2 ? sn : TAIL));
        ushort8v n1 = *(const ushort8v*)(csr + (sn + 8 < r2 ? sn + 8 : TAIL));
        // 4 halves at bases s, s+4, s+8, s+12: sum 4 rows, then route.
#pragma unroll
        for (int h = 0; h < 4; ++h) {
            float t[8] = {0, 0, 0, 0, 0, 0, 0, 0};
#pragma unroll
            for (int j = 0; j < 4; ++j) {
                float d[8];
                fp8x8_decode((h < 2 ? v0 : v1)[(h & 1) * 4 + j], d);
#pragma unroll
                for (int f = 0; f < 8; ++f) t[f] += d[f];
            }
            int bh = s + h * 4;
            bool bA = bh < r1;   // half fully in row A (4-aligned bounds)
            bool bV = bh < r2;   // half within this group's range at all
#pragma unroll
            for (int f = 0; f < 8; ++f) {
                float x = bA ? t[f] : 0.0f;
                float v = bV ? t[f] : 0.0f;
                aA[f] += x;
                aB[f] += v - x;
            }
        }
        i0 = n0;
        i1 = n1;
        s = sn;
    }
}

// ------------------------------------------------------ init + weight prep --
// Blocks [0,NB): zero deg/psum/sentinel rows. Blocks [NB,NB+3): swizzle W.
__global__ __launch_bounds__(256) void init_kernel(
    int* __restrict__ deg, float* __restrict__ psum,
    unsigned char* __restrict__ bufA, unsigned char* __restrict__ bufB, int N,
    int NB, const float* __restrict__ W0, const float* __restrict__ W1,
    const float* __restrict__ W2, unsigned short* __restrict__ Wz) {
    int b = blockIdx.x;
    if (b >= NB) {
        int wsel = b - NB;
        const float* W = (wsel == 0) ? W0 : (wsel == 1) ? W1 : W2;
        unsigned short* dst = Wz + wsel * HID * HID;
        for (int e = threadIdx.x; e < HID * HID; e += blockDim.x) {
            int k = e / HID, n = e % HID;
            int nt = n >> 4, kki = k >> 5, quad = (k >> 3) & 3, j = k & 7;
            int lane = (n & 15) | (quad << 4);
            dst[(((nt * 3 + kki) * 64 + lane) << 3) | j] = f32_to_bf16(W[e]);
        }
        return;
    }
    int i = b * 256 + threadIdx.x;
    if (i < N) deg[i] = 0;
    if (i < NGRAPHS * HID + NGRAPHS) psum[i] = 0.0f;
    if (i < HID) {
        bufA[(size_t)SENT * HID + i] = 0;  // fp8 0x00 == 0.0
        bufB[(size_t)SENT * HID + i] = 0;
    }
}

// ---------------------------------------------------------------- degree ----
__global__ void deg_kernel(const int* __restrict__ dst, int* __restrict__ deg,
                           int n_edges) {
    int t = blockIdx.x * blockDim.x + threadIdx.x;
    int e0 = t * 4;
    if (e0 + 4 <= n_edges) {
        int4 d4 = *(const int4*)(dst + e0);
        atomicAdd(&deg[d4.x], 1);
        atomicAdd(&deg[d4.y], 1);
        atomicAdd(&deg[d4.z], 1);
        atomicAdd(&deg[d4.w], 1);
    } else {
        for (int e = e0; e < n_edges; e++) atomicAdd(&deg[dst[e]], 1);
    }
}

// ------------------------------------------- scan (padded to 4) + dinv ------
__global__ __launch_bounds__(256) void scan_phaseA(const int* __restrict__ deg,
                                                   float* __restrict__ dinv,
                                                   int* __restrict__ blocksum,
                                                   int N) {
    int i = blockIdx.x * 256 + threadIdx.x;
    int d = (i < N) ? deg[i] : 0;
    if (i < N) dinv[i] = rsqrtf((float)d + 1.0f);
    int v = (d + 3) & ~3;  // padded degree (pad-4)
#pragma unroll
    for (int off = 32; off > 0; off >>= 1) v += __shfl_down(v, off, 64);
    __shared__ int s[4];
    if ((threadIdx.x & 63) == 0) s[threadIdx.x >> 6] = v;
    __syncthreads();
    if (threadIdx.x == 0) blocksum[blockIdx.x] = s[0] + s[1] + s[2] + s[3];
}

__global__ __launch_bounds__(256) void scan_phaseC(const int* __restrict__ deg,
                                                   const int* __restrict__ blocksum,
                                                   int* __restrict__ rowptr,
                                                   int* __restrict__ cursor,
                                                   int N, int NB) {
    int t = threadIdx.x;
    int mine = (t < NB && t < blockIdx.x) ? blocksum[t] : 0;
#pragma unroll
    for (int off = 32; off > 0; off >>= 1) mine += __shfl_down(mine, off, 64);
    __shared__ int ps[4];
    if ((t & 63) == 0) ps[t >> 6] = mine;
    __syncthreads();
    int pref = ps[0] + ps[1] + ps[2] + ps[3];

    __shared__ int s[256];
    int i = blockIdx.x * 256 + t;
    int own = (i < N) ? (deg[i] + 3) & ~3 : 0;  // pad-4
    s[t] = own;
    __syncthreads();
#pragma unroll
    for (int off = 1; off < 256; off <<= 1) {
        int v = (t >= off) ? s[t - off] : 0;
        __syncthreads();
        s[t] += v;
        __syncthreads();
    }
    if (i < N) {
        int r = pref + s[t] - own;
        rowptr[i] = r;
        cursor[i] = r;
        if (i == N - 1) rowptr[N] = r + own;
    }
}

// ------------------------------------------------------------------ fill ----
__global__ void csr_fill(const int* __restrict__ src, const int* __restrict__ dst,
                         int* __restrict__ cursor,
                         unsigned short* __restrict__ csr_src, int n_edges) {
    int t = blockIdx.x * blockDim.x + threadIdx.x;
    int e0 = t * 8;
    if (e0 + 8 <= n_edges) {
        int4 da = *(const int4*)(dst + e0);
        int4 db = *(const int4*)(dst + e0 + 4);
        int4 sa = *(const int4*)(src + e0);
        int4 sb = *(const int4*)(src + e0 + 4);
        int p0 = atomicAdd(&cursor[da.x], 1);
        int p1 = atomicAdd(&cursor[da.y], 1);
        int p2 = atomicAdd(&cursor[da.z], 1);
        int p3 = atomicAdd(&cursor[da.w], 1);
        int p4 = atomicAdd(&cursor[db.x], 1);
        int p5 = atomicAdd(&cursor[db.y], 1);
        int p6 = atomicAdd(&cursor[db.z], 1);
        int p7 = atomicAdd(&cursor[db.w], 1);
        csr_src[p0] = (unsigned short)sa.x;
        csr_src[p1] = (unsigned short)sa.y;
        csr_src[p2] = (unsigned short)sa.z;
        csr_src[p3] = (unsigned short)sa.w;
        csr_src[p4] = (unsigned short)sb.x;
        csr_src[p5] = (unsigned short)sb.y;
        csr_src[p6] = (unsigned short)sb.z;
        csr_src[p7] = (unsigned short)sb.w;
    } else {
        for (int e = e0; e < n_edges; e++) {
            int p = atomicAdd(&cursor[dst[e]], 1);
            csr_src[p] = (unsigned short)src[e];
        }
    }
}

// ----------------------------------------------------- GEMM0 (f32 input) ----
__global__ __launch_bounds__(256) void gemm0_f32(
    const float* __restrict__ X, const unsigned short* __restrict__ Wz,
    const float* __restrict__ dinv, unsigned char* __restrict__ Out, int Mtiles) {
    int wv = threadIdx.x >> 6;
    int lane = threadIdx.x & 63;
    int quad = lane >> 4;
    int mrow = lane & 15;
    int tt = blockIdx.x * 2 + (wv >> 1);
    int half = wv & 1;
    if (tt >= Mtiles) return;

    short8 bfrag[9];
    const short8* Wz8 = (const short8*)Wz;
#pragma unroll
    for (int f = 0; f < 9; f++) bfrag[f] = Wz8[(half * 9 + f) * 64 + lane];

    int m0 = tt * 16;
    const float* arow = X + (size_t)(m0 + mrow) * HID + quad * 8;
    short8 a[3];
#pragma unroll
    for (int kb = 0; kb < 3; kb++) {
        float4 u = *(const float4*)(arow + kb * 32);
        float4 v = *(const float4*)(arow + kb * 32 + 4);
        short8 t;
        t[0] = (short)f32_to_bf16(u.x); t[1] = (short)f32_to_bf16(u.y);
        t[2] = (short)f32_to_bf16(u.z); t[3] = (short)f32_to_bf16(u.w);
        t[4] = (short)f32_to_bf16(v.x); t[5] = (short)f32_to_bf16(v.y);
        t[6] = (short)f32_to_bf16(v.z); t[7] = (short)f32_to_bf16(v.w);
        a[kb] = t;
    }
    float dscale[4];
#pragma unroll
    for (int r = 0; r < 4; r++) dscale[r] = dinv[m0 + quad * 4 + r];
    unsigned char* orow = Out + (size_t)m0 * HID;
#pragma unroll
    for (int ntl = 0; ntl < 3; ntl++) {
        int nt = half * 3 + ntl;
        floatx4 c = {0.0f, 0.0f, 0.0f, 0.0f};
        c = __builtin_amdgcn_mfma_f32_16x16x32_bf16(a[0], bfrag[ntl * 3 + 0], c, 0, 0, 0);
        c = __builtin_amdgcn_mfma_f32_16x16x32_bf16(a[1], bfrag[ntl * 3 + 1], c, 0, 0, 0);
        c = __builtin_amdgcn_mfma_f32_16x16x32_bf16(a[2], bfrag[ntl * 3 + 2], c, 0, 0, 0);
#pragma unroll
        for (int r = 0; r < 4; r++)
            orow[(size_t)(quad * 4 + r) * HID + nt * 16 + mrow] =
                f32_to_fp8(c[r] * dscale[r]);
    }
}

// ------------------------------------------------ fused gather + GEMM -------
// Wave gathers 8 rows as 4 groups x 2 rows (fp8 input, pad-4 CSR), writes
// relu(a*dinv+b) as bf16 into the MFMA LDS tile; GEMM epilogue writes fp8.
__global__ __launch_bounds__(256) void fused_gather_gemm(
    const unsigned char* __restrict__ h8, const int* __restrict__ rowptr,
    const unsigned short* __restrict__ csr, const float* __restrict__ dinv,
    const float* __restrict__ bias, const unsigned short* __restrict__ Wz,
    unsigned char* __restrict__ Out, int Mtiles, int N) {
    __shared__ unsigned short tile[2][16][104];  // stride 104
    int wv = threadIdx.x >> 6;
    int lane = threadIdx.x & 63;
    int quad = lane >> 4;
    int mrow = lane & 15;
    int tsel = wv >> 1;
    int half = wv & 1;
    int tt = blockIdx.x * 2 + tsel;
    bool active = tt < Mtiles;
    int g = lane >> 4;
    int p = lane & 15;
    int pe = (p < 12) ? p : 11;
    int pe8 = pe * 8;

    if (active) {
        int TAIL = rowptr[N];
        int j0 = half * 8 + g * 2;
        int na = tt * 16 + j0;
        int r0 = rowptr[na], r1 = rowptr[na + 1], r2 = rowptr[na + 2];
        float da = dinv[na], db = dinv[na + 1];
        float aA[8], aB[8];
        uint2v sva = *(const uint2v*)(h8 + (size_t)na * HID + pe8);
        uint2v svb = *(const uint2v*)(h8 + (size_t)(na + 1) * HID + pe8);
        fp8x8_decode(sva, aA);
        fp8x8_decode(svb, aB);
        int it2 = (r2 - r0 + 15) >> 4;
        int o = __shfl_xor(it2, 16, 64);
        it2 = it2 > o ? it2 : o;
        o = __shfl_xor(it2, 32, 64);
        it2 = it2 > o ? it2 : o;
        gather_core4(h8, csr, r0, r1, r2, TAIL, it2, pe8, aA, aB);
        float4 bb0 = *(const float4*)(bias + pe8);
        float4 bb1 = *(const float4*)(bias + pe8 + 4);
        float bv[8] = {bb0.x, bb0.y, bb0.z, bb0.w, bb1.x, bb1.y, bb1.z, bb1.w};
        if (p < 12) {
            ushort8v oA, oB;
#pragma unroll
            for (int f = 0; f < 8; ++f) {
                oA[f] = f32_to_bf16(fmaxf(aA[f] * da + bv[f], 0.0f));
                oB[f] = f32_to_bf16(fmaxf(aB[f] * db + bv[f], 0.0f));
            }
            *(ushort8v*)(&tile[tsel][j0][pe8]) = oA;
            *(ushort8v*)(&tile[tsel][j0 + 1][pe8]) = oB;
        }
    }
    __syncthreads();
    if (!active) return;

    short8 bfrag[9];
    const short8* Wz8 = (const short8*)Wz;
#pragma unroll
    for (int f = 0; f < 9; f++) bfrag[f] = Wz8[(half * 9 + f) * 64 + lane];

    const unsigned short* tp = &tile[tsel][0][0];
    short8 a[3];
#pragma unroll
    for (int kb = 0; kb < 3; kb++)
        a[kb] = *(const short8*)(tp + mrow * 104 + quad * 8 + kb * 32);
    int n0 = tt * 16;
    float dscale[4];
#pragma unroll
    for (int r = 0; r < 4; r++) dscale[r] = dinv[n0 + quad * 4 + r];
    unsigned char* orow = Out + (size_t)n0 * HID;
#pragma unroll
    for (int ntl = 0; ntl < 3; ntl++) {
        int nt = half * 3 + ntl;
        floatx4 c = {0.0f, 0.0f, 0.0f, 0.0f};
        c = __builtin_amdgcn_mfma_f32_16x16x32_bf16(a[0], bfrag[ntl * 3 + 0], c, 0, 0, 0);
        c = __builtin_amdgcn_mfma_f32_16x16x32_bf16(a[1], bfrag[ntl * 3 + 1], c, 0, 0, 0);
        c = __builtin_amdgcn_mfma_f32_16x16x32_bf16(a[2], bfrag[ntl * 3 + 2], c, 0, 0, 0);
#pragma unroll
        for (int r = 0; r < 4; r++)
            orow[(size_t)(quad * 4 + r) * HID + nt * 16 + mrow] =
                f32_to_fp8(c[r] * dscale[r]);
    }
}

// ------------------------------------------------- fused gather + pool ------
// Wide fp8 gather of 8 rows/wave (pad-4 CSR); stage f32 outputs in per-wave
// LDS; then a BLOCK-level run-length pool: 96 threads reduce all 32 rows of
// the block in LDS and emit ~1 atomicAdd per feature per graph-run
// (~104 atomics/block vs ~424 with per-wave flushes).
__global__ __launch_bounds__(256) void gather_pool(
    const unsigned char* __restrict__ h8, const int* __restrict__ rowptr,
    const unsigned short* __restrict__ csr, const float* __restrict__ dinv,
    const float* __restrict__ bias, const int* __restrict__ batch,
    float* __restrict__ psum, float* __restrict__ pcnt, int Ntiles8, int N) {
    __shared__ float stage[4][8][96];  // 12 KB, per-wave region
    int wv = threadIdx.x >> 6;
    int lane = threadIdx.x & 63;
    int tt = blockIdx.x * 4 + wv;
    bool active = tt < Ntiles8;
    int g = lane >> 4;
    int p = lane & 15;
    int pe = (p < 12) ? p : 11;
    int pe8 = pe * 8;

    if (active) {
        int TAIL = rowptr[N];
        int n0 = tt * 8;
        int na = n0 + g * 2;
        int r0 = rowptr[na], r1 = rowptr[na + 1], r2 = rowptr[na + 2];
        float da = dinv[na], db = dinv[na + 1];
        float aA[8], aB[8];
        uint2v sva = *(const uint2v*)(h8 + (size_t)na * HID + pe8);
        uint2v svb = *(const uint2v*)(h8 + (size_t)(na + 1) * HID + pe8);
        fp8x8_decode(sva, aA);
        fp8x8_decode(svb, aB);
        int it2 = (r2 - r0 + 15) >> 4;
        int o = __shfl_xor(it2, 16, 64);
        it2 = it2 > o ? it2 : o;
        o = __shfl_xor(it2, 32, 64);
        it2 = it2 > o ? it2 : o;
        gather_core4(h8, csr, r0, r1, r2, TAIL, it2, pe8, aA, aB);
        float4 bb0 = *(const float4*)(bias + pe8);
        float4 bb1 = *(const float4*)(bias + pe8 + 4);
        float bv[8] = {bb0.x, bb0.y, bb0.z, bb0.w, bb1.x, bb1.y, bb1.z, bb1.w};
        if (p < 12) {  // last layer: no ReLU
            floatx4 oa0 = {aA[0] * da + bv[0], aA[1] * da + bv[1],
                           aA[2] * da + bv[2], aA[3] * da + bv[3]};
            floatx4 oa1 = {aA[4] * da + bv[4], aA[5] * da + bv[5],
                           aA[6] * da + bv[6], aA[7] * da + bv[7]};
            floatx4 ob0 = {aB[0] * db + bv[0], aB[1] * db + bv[1],
                           aB[2] * db + bv[2], aB[3] * db + bv[3]};
            floatx4 ob1 = {aB[4] * db + bv[4], aB[5] * db + bv[5],
                           aB[6] * db + bv[6], aB[7] * db + bv[7]};
            *(floatx4*)(&stage[wv][g * 2][pe8]) = oa0;
            *(floatx4*)(&stage[wv][g * 2][pe8 + 4]) = oa1;
            *(floatx4*)(&stage[wv][g * 2 + 1][pe8]) = ob0;
            *(floatx4*)(&stage[wv][g * 2 + 1][pe8 + 4]) = ob1;
        }
    }
    __syncthreads();

    // ---- block-level run-length pool over 32 rows (batch is sorted) ----
    int t = threadIdx.x;
    if (t < 96) {
        int n0b = blockIdx.x * 32;
        int limit = N - n0b;
        if (limit > 32) limit = 32;
        int g_cur = batch[n0b];
        float s = 0.0f;
        int cnt = 0;
        for (int j = 0; j < limit; ++j) {
            int gb = batch[n0b + j];
            if (gb != g_cur) {  // uniform across threads (scalar batch value)
                atomicAdd(&psum[g_cur * HID + t], s);
                if (t == 0) atomicAdd(&pcnt[g_cur], (float)cnt);
                s = 0.0f;
                cnt = 0;
                g_cur = gb;
            }
            s += stage[j >> 3][j & 7][t];
            cnt++;
        }
        atomicAdd(&psum[g_cur * HID + t], s);
        if (t == 0) atomicAdd(&pcnt[g_cur], (float)cnt);
    }
}

// ---------------------------------------------------------------- head ------
__global__ __launch_bounds__(640) void final_kernel(
    const float* __restrict__ sums, const float* __restrict__ cnts,
    const float* __restrict__ Wlin, const float* __restrict__ blin,
    float* __restrict__ out) {
    int t = threadIdx.x;
    if (t >= NGRAPHS * 10) return;
    int g = t / 10;
    int c = t % 10;
    float denom = fmaxf(cnts[g], 1.0f);
    float acc = blin[c];
#pragma unroll
    for (int f = 0; f < HID; f++)
        acc += (sums[g * HID + f] / denom) * Wlin[f * 10 + c];
    out[t] = acc;
}

// ---------------------------------------------------------------- launch ----
extern "C" void kernel_launch(void* const* d_in, const int* in_sizes, int n_in,
                              void* d_out, int out_size, void* d_ws,
                              size_t ws_size, hipStream_t stream) {
    const float* x = (const float*)d_in[0];
    const int* edge = (const int*)d_in[1];
    const int* batch = (const int*)d_in[2];
    const float* W[3] = {(const float*)d_in[3], (const float*)d_in[5],
                         (const float*)d_in[7]};
    const float* B[3] = {(const float*)d_in[4], (const float*)d_in[6],
                         (const float*)d_in[8]};
    const float* Wlin = (const float*)d_in[9];
    const float* blin = (const float*)d_in[10];
    float* out = (float*)d_out;

    int N = in_sizes[0] / HID;  // 50000
    int E = in_sizes[1] / 2;    // 800000
    const int* src = edge;
    const int* dst = edge + E;
    int NB = (N + 255) / 256;   // 196

    char* ws = (char*)d_ws;
    size_t off = 0;
    auto alloc = [&](size_t bytes) {
        void* p = ws + off;
        off += (bytes + 255) & ~(size_t)255;
        return p;
    };
    int* deg = (int*)alloc((size_t)N * 4);
    float* dinv = (float*)alloc((size_t)N * 4);
    int* rowptr = (int*)alloc(((size_t)N + 1) * 4);
    int* cursor = (int*)alloc((size_t)N * 4);
    int* blocksum = (int*)alloc((size_t)NB * 4);
    size_t csr_cap = (size_t)E + 4 * (size_t)N;  // pad-4
    unsigned short* csr_src = (unsigned short*)alloc(csr_cap * 2 + 64);
    unsigned short* Wz = (unsigned short*)alloc(3 * HID * HID * 2);
    unsigned char* bufA = (unsigned char*)alloc((size_t)NROWS * HID);  // fp8
    unsigned char* bufB = (unsigned char*)alloc((size_t)NROWS * HID);  // fp8
    float* psum = (float*)alloc((NGRAPHS * HID + NGRAPHS) * 4);
    float* pcnt = psum + NGRAPHS * HID;

    // --- CSR build + weight prep ---
    hipMemsetAsync(csr_src, 0xC3, csr_cap * 2, stream);  // pads -> sentinel row
    init_kernel<<<NB + 3, 256, 0, stream>>>(deg, psum, bufA, bufB, N, NB,
                                            W[0], W[1], W[2], Wz);
    deg_kernel<<<(E / 4 + 255) / 256, 256, 0, stream>>>(dst, deg, E);
    scan_phaseA<<<NB, 256, 0, stream>>>(deg, dinv, blocksum, N);
    scan_phaseC<<<NB, 256, 0, stream>>>(deg, blocksum, rowptr, cursor, N, NB);
    csr_fill<<<(E / 8 + 255) / 256, 256, 0, stream>>>(src, dst, cursor, csr_src, E);

    int Mtiles = (N + 15) / 16;           // 3125
    int grid2 = (Mtiles + 1) / 2;         // 1563 (2 tiles/block)
    int Ntiles8 = (N + 7) / 8;            // 6250
    int gridp = (Ntiles8 + 3) / 4;        // 1563

    gemm0_f32<<<grid2, 256, 0, stream>>>(x, Wz, dinv, bufA, Mtiles);
    fused_gather_gemm<<<grid2, 256, 0, stream>>>(
        bufA, rowptr, csr_src, dinv, B[0], Wz + 1 * HID * HID, bufB, Mtiles, N);
    fused_gather_gemm<<<grid2, 256, 0, stream>>>(
        bufB, rowptr, csr_src, dinv, B[1], Wz + 2 * HID * HID, bufA, Mtiles, N);
    gather_pool<<<gridp, 256, 0, stream>>>(bufA, rowptr, csr_src, dinv, B[2],
                                           batch, psum, pcnt, Ntiles8, N);
    final_kernel<<<1, 640, 0, stream>>>(psum, pcnt, Wlin, blin, out);
}

// Round 9
// 270.277 us; speedup vs baseline: 1.1996x; 1.0083x over previous
//
#include <hip/hip_runtime.h>
#include <hip/hip_bf16.h>

#define HID 96
#define NGRAPHS 64
#define SENT 0xC3C3u   // 50115: sentinel row (zeroed) for CSR padding
#define NROWS 50116    // N + sentinel row
#define NSPLIT 8       // psum copies (blockIdx&7 ~ XCD round-robin)

typedef __attribute__((ext_vector_type(8))) short short8;
typedef __attribute__((ext_vector_type(4))) float floatx4;
typedef __attribute__((ext_vector_type(2))) float floatx2;
typedef __attribute__((ext_vector_type(8))) unsigned short ushort8v;
typedef __attribute__((ext_vector_type(2))) unsigned int uint2v;

__device__ __forceinline__ unsigned short f32_to_bf16(float f) {
    unsigned int u = __builtin_bit_cast(unsigned int, f);
    u += 0x7fff + ((u >> 16) & 1);  // RNE
    return (unsigned short)(u >> 16);
}
// Single f32 -> fp8 e4m3 byte (HW cvt; byte0 of the packed result).
__device__ __forceinline__ unsigned char f32_to_fp8(float f) {
    return (unsigned char)(__builtin_amdgcn_cvt_pk_fp8_f32(f, f, 0, false) & 0xff);
}
// Decode one fp8x8 fragment into f32[8].
__device__ __forceinline__ void fp8x8_decode(uint2v u, float* __restrict__ o) {
    floatx2 a0 = __builtin_amdgcn_cvt_pk_f32_fp8(u[0], false);
    floatx2 a1 = __builtin_amdgcn_cvt_pk_f32_fp8(u[0], true);
    floatx2 a2 = __builtin_amdgcn_cvt_pk_f32_fp8(u[1], false);
    floatx2 a3 = __builtin_amdgcn_cvt_pk_f32_fp8(u[1], true);
    o[0] = a0[0]; o[1] = a0[1]; o[2] = a1[0]; o[3] = a1[1];
    o[4] = a2[0]; o[5] = a2[1]; o[6] = a3[0]; o[7] = a3[1];
}

// ---------------------------------------------------------------------------
// fp8 wide-gather core, PAD-4 rows, 2-DEEP index prefetch. Wave = 4 groups x
// 16 lanes; lane p<12 loads 8 features (uint2v, 8B) of one edge-row (96B).
// Each group owns 2 consecutive CSR rows [r0,r2) with boundary r1 (all
// multiples of 4). Index vectors for iterations N and N+1 are held in
// registers; iteration N fetches N+2's — so the h-loads of iteration N use
// indices whose load retired an iteration ago (CSR latency off the chain).
// Slots processed in 4-slot halves routed into aA/aB/discard by predicate.
// ---------------------------------------------------------------------------
__device__ __forceinline__ void gather_core4(
    const unsigned char* __restrict__ h8, const unsigned short* __restrict__ csr,
    int r0, int r1, int r2, int TAIL, int it2, int pe8,
    float* __restrict__ aA, float* __restrict__ aB) {
    int s = r0;
    ushort8v ia0 = *(const ushort8v*)(csr + (s      < r2 ? s      : TAIL));
    ushort8v ia1 = *(const ushort8v*)(csr + (s + 8  < r2 ? s + 8  : TAIL));
    ushort8v ib0 = *(const ushort8v*)(csr + (s + 16 < r2 ? s + 16 : TAIL));
    ushort8v ib1 = *(const ushort8v*)(csr + (s + 24 < r2 ? s + 24 : TAIL));
    for (int it = 0; it < it2; ++it) {
        uint2v v0[8], v1[8];
#pragma unroll
        for (int j = 0; j < 8; ++j)
            v0[j] = *(const uint2v*)(h8 + (int)ia0[j] * HID + pe8);
#pragma unroll
        for (int j = 0; j < 8; ++j)
            v1[j] = *(const uint2v*)(h8 + (int)ia1[j] * HID + pe8);
        int sp = s + 32;
        ushort8v n0 = *(const ushort8v*)(csr + (sp     < r2 ? sp     : TAIL));
        ushort8v n1 = *(const ushort8v*)(csr + (sp + 8 < r2 ? sp + 8 : TAIL));
        // 4 halves at bases s, s+4, s+8, s+12: sum 4 rows, then route.
#pragma unroll
        for (int h = 0; h < 4; ++h) {
            float t[8] = {0, 0, 0, 0, 0, 0, 0, 0};
#pragma unroll
            for (int j = 0; j < 4; ++j) {
                float d[8];
                fp8x8_decode((h < 2 ? v0 : v1)[(h & 1) * 4 + j], d);
#pragma unroll
                for (int f = 0; f < 8; ++f) t[f] += d[f];
            }
            int bh = s + h * 4;
            bool bA = bh < r1;   // half fully in row A (4-aligned bounds)
            bool bV = bh < r2;   // half within this group's range at all
#pragma unroll
            for (int f = 0; f < 8; ++f) {
                float x = bA ? t[f] : 0.0f;
                float v = bV ? t[f] : 0.0f;
                aA[f] += x;
                aB[f] += v - x;
            }
        }
        ia0 = ib0;
        ia1 = ib1;
        ib0 = n0;
        ib1 = n1;
        s += 16;
    }
}

// ------------------------------------------------------ init + weight prep --
// Blocks [0,NB): zero deg/psum-copies/sentinel rows. Blocks [NB,NB+3): swizzle W.
__global__ __launch_bounds__(256) void init_kernel(
    int* __restrict__ deg, float* __restrict__ psum,
    unsigned char* __restrict__ bufA, unsigned char* __restrict__ bufB, int N,
    int NB, const float* __restrict__ W0, const float* __restrict__ W1,
    const float* __restrict__ W2, unsigned short* __restrict__ Wz) {
    int b = blockIdx.x;
    if (b >= NB) {
        int wsel = b - NB;
        const float* W = (wsel == 0) ? W0 : (wsel == 1) ? W1 : W2;
        unsigned short* dst = Wz + wsel * HID * HID;
        for (int e = threadIdx.x; e < HID * HID; e += blockDim.x) {
            int k = e / HID, n = e % HID;
            int nt = n >> 4, kki = k >> 5, quad = (k >> 3) & 3, j = k & 7;
            int lane = (n & 15) | (quad << 4);
            dst[(((nt * 3 + kki) * 64 + lane) << 3) | j] = f32_to_bf16(W[e]);
        }
        return;
    }
    int i = b * 256 + threadIdx.x;
    if (i < N) deg[i] = 0;
    if (i < NSPLIT * (NGRAPHS * HID + NGRAPHS)) psum[i] = 0.0f;
    if (i < HID) {
        bufA[(size_t)SENT * HID + i] = 0;  // fp8 0x00 == 0.0
        bufB[(size_t)SENT * HID + i] = 0;
    }
}

// ---------------------------------------------------------------- degree ----
__global__ void deg_kernel(const int* __restrict__ dst, int* __restrict__ deg,
                           int n_edges) {
    int t = blockIdx.x * blockDim.x + threadIdx.x;
    int e0 = t * 4;
    if (e0 + 4 <= n_edges) {
        int4 d4 = *(const int4*)(dst + e0);
        atomicAdd(&deg[d4.x], 1);
        atomicAdd(&deg[d4.y], 1);
        atomicAdd(&deg[d4.z], 1);
        atomicAdd(&deg[d4.w], 1);
    } else {
        for (int e = e0; e < n_edges; e++) atomicAdd(&deg[dst[e]], 1);
    }
}

// ------------------------------------------- scan (padded to 4) + dinv ------
__global__ __launch_bounds__(256) void scan_phaseA(const int* __restrict__ deg,
                                                   float* __restrict__ dinv,
                                                   int* __restrict__ blocksum,
                                                   int N) {
    int i = blockIdx.x * 256 + threadIdx.x;
    int d = (i < N) ? deg[i] : 0;
    if (i < N) dinv[i] = rsqrtf((float)d + 1.0f);
    int v = (d + 3) & ~3;  // padded degree (pad-4)
#pragma unroll
    for (int off = 32; off > 0; off >>= 1) v += __shfl_down(v, off, 64);
    __shared__ int s[4];
    if ((threadIdx.x & 63) == 0) s[threadIdx.x >> 6] = v;
    __syncthreads();
    if (threadIdx.x == 0) blocksum[blockIdx.x] = s[0] + s[1] + s[2] + s[3];
}

__global__ __launch_bounds__(256) void scan_phaseC(const int* __restrict__ deg,
                                                   const int* __restrict__ blocksum,
                                                   int* __restrict__ rowptr,
                                                   int* __restrict__ cursor,
                                                   int N, int NB) {
    int t = threadIdx.x;
    int mine = (t < NB && t < blockIdx.x) ? blocksum[t] : 0;
#pragma unroll
    for (int off = 32; off > 0; off >>= 1) mine += __shfl_down(mine, off, 64);
    __shared__ int ps[4];
    if ((t & 63) == 0) ps[t >> 6] = mine;
    __syncthreads();
    int pref = ps[0] + ps[1] + ps[2] + ps[3];

    __shared__ int s[256];
    int i = blockIdx.x * 256 + t;
    int own = (i < N) ? (deg[i] + 3) & ~3 : 0;  // pad-4
    s[t] = own;
    __syncthreads();
#pragma unroll
    for (int off = 1; off < 256; off <<= 1) {
        int v = (t >= off) ? s[t - off] : 0;
        __syncthreads();
        s[t] += v;
        __syncthreads();
    }
    if (i < N) {
        int r = pref + s[t] - own;
        rowptr[i] = r;
        cursor[i] = r;
        if (i == N - 1) rowptr[N] = r + own;
    }
}

// ------------------------------------------------------------------ fill ----
__global__ void csr_fill(const int* __restrict__ src, const int* __restrict__ dst,
                         int* __restrict__ cursor,
                         unsigned short* __restrict__ csr_src, int n_edges) {
    int t = blockIdx.x * blockDim.x + threadIdx.x;
    int e0 = t * 8;
    if (e0 + 8 <= n_edges) {
        int4 da = *(const int4*)(dst + e0);
        int4 db = *(const int4*)(dst + e0 + 4);
        int4 sa = *(const int4*)(src + e0);
        int4 sb = *(const int4*)(src + e0 + 4);
        int p0 = atomicAdd(&cursor[da.x], 1);
        int p1 = atomicAdd(&cursor[da.y], 1);
        int p2 = atomicAdd(&cursor[da.z], 1);
        int p3 = atomicAdd(&cursor[da.w], 1);
        int p4 = atomicAdd(&cursor[db.x], 1);
        int p5 = atomicAdd(&cursor[db.y], 1);
        int p6 = atomicAdd(&cursor[db.z], 1);
        int p7 = atomicAdd(&cursor[db.w], 1);
        csr_src[p0] = (unsigned short)sa.x;
        csr_src[p1] = (unsigned short)sa.y;
        csr_src[p2] = (unsigned short)sa.z;
        csr_src[p3] = (unsigned short)sa.w;
        csr_src[p4] = (unsigned short)sb.x;
        csr_src[p5] = (unsigned short)sb.y;
        csr_src[p6] = (unsigned short)sb.z;
        csr_src[p7] = (unsigned short)sb.w;
    } else {
        for (int e = e0; e < n_edges; e++) {
            int p = atomicAdd(&cursor[dst[e]], 1);
            csr_src[p] = (unsigned short)src[e];
        }
    }
}

// ----------------------------------------------------- GEMM0 (f32 input) ----
__global__ __launch_bounds__(256) void gemm0_f32(
    const float* __restrict__ X, const unsigned short* __restrict__ Wz,
    const float* __restrict__ dinv, unsigned char* __restrict__ Out, int Mtiles) {
    int wv = threadIdx.x >> 6;
    int lane = threadIdx.x & 63;
    int quad = lane >> 4;
    int mrow = lane & 15;
    int tt = blockIdx.x * 2 + (wv >> 1);
    int half = wv & 1;
    if (tt >= Mtiles) return;

    short8 bfrag[9];
    const short8* Wz8 = (const short8*)Wz;
#pragma unroll
    for (int f = 0; f < 9; f++) bfrag[f] = Wz8[(half * 9 + f) * 64 + lane];

    int m0 = tt * 16;
    const float* arow = X + (size_t)(m0 + mrow) * HID + quad * 8;
    short8 a[3];
#pragma unroll
    for (int kb = 0; kb < 3; kb++) {
        float4 u = *(const float4*)(arow + kb * 32);
        float4 v = *(const float4*)(arow + kb * 32 + 4);
        short8 t;
        t[0] = (short)f32_to_bf16(u.x); t[1] = (short)f32_to_bf16(u.y);
        t[2] = (short)f32_to_bf16(u.z); t[3] = (short)f32_to_bf16(u.w);
        t[4] = (short)f32_to_bf16(v.x); t[5] = (short)f32_to_bf16(v.y);
        t[6] = (short)f32_to_bf16(v.z); t[7] = (short)f32_to_bf16(v.w);
        a[kb] = t;
    }
    float dscale[4];
#pragma unroll
    for (int r = 0; r < 4; r++) dscale[r] = dinv[m0 + quad * 4 + r];
    unsigned char* orow = Out + (size_t)m0 * HID;
#pragma unroll
    for (int ntl = 0; ntl < 3; ntl++) {
        int nt = half * 3 + ntl;
        floatx4 c = {0.0f, 0.0f, 0.0f, 0.0f};
        c = __builtin_amdgcn_mfma_f32_16x16x32_bf16(a[0], bfrag[ntl * 3 + 0], c, 0, 0, 0);
        c = __builtin_amdgcn_mfma_f32_16x16x32_bf16(a[1], bfrag[ntl * 3 + 1], c, 0, 0, 0);
        c = __builtin_amdgcn_mfma_f32_16x16x32_bf16(a[2], bfrag[ntl * 3 + 2], c, 0, 0, 0);
#pragma unroll
        for (int r = 0; r < 4; r++)
            orow[(size_t)(quad * 4 + r) * HID + nt * 16 + mrow] =
                f32_to_fp8(c[r] * dscale[r]);
    }
}

// ------------------------------------------------ fused gather + GEMM -------
// Wave gathers 8 rows as 4 groups x 2 rows (fp8 input, pad-4 CSR, 2-deep
// prefetch), writes relu(a*dinv+b) as bf16 into the MFMA LDS tile; GEMM
// epilogue writes fp8.
__global__ __launch_bounds__(256) void fused_gather_gemm(
    const unsigned char* __restrict__ h8, const int* __restrict__ rowptr,
    const unsigned short* __restrict__ csr, const float* __restrict__ dinv,
    const float* __restrict__ bias, const unsigned short* __restrict__ Wz,
    unsigned char* __restrict__ Out, int Mtiles, int N) {
    __shared__ unsigned short tile[2][16][104];  // stride 104
    int wv = threadIdx.x >> 6;
    int lane = threadIdx.x & 63;
    int quad = lane >> 4;
    int mrow = lane & 15;
    int tsel = wv >> 1;
    int half = wv & 1;
    int tt = blockIdx.x * 2 + tsel;
    bool active = tt < Mtiles;
    int g = lane >> 4;
    int p = lane & 15;
    int pe = (p < 12) ? p : 11;
    int pe8 = pe * 8;

    if (active) {
        int TAIL = rowptr[N];
        int j0 = half * 8 + g * 2;
        int na = tt * 16 + j0;
        int r0 = rowptr[na], r1 = rowptr[na + 1], r2 = rowptr[na + 2];
        float da = dinv[na], db = dinv[na + 1];
        float aA[8], aB[8];
        uint2v sva = *(const uint2v*)(h8 + (size_t)na * HID + pe8);
        uint2v svb = *(const uint2v*)(h8 + (size_t)(na + 1) * HID + pe8);
        fp8x8_decode(sva, aA);
        fp8x8_decode(svb, aB);
        int it2 = (r2 - r0 + 15) >> 4;
        int o = __shfl_xor(it2, 16, 64);
        it2 = it2 > o ? it2 : o;
        o = __shfl_xor(it2, 32, 64);
        it2 = it2 > o ? it2 : o;
        gather_core4(h8, csr, r0, r1, r2, TAIL, it2, pe8, aA, aB);
        float4 bb0 = *(const float4*)(bias + pe8);
        float4 bb1 = *(const float4*)(bias + pe8 + 4);
        float bv[8] = {bb0.x, bb0.y, bb0.z, bb0.w, bb1.x, bb1.y, bb1.z, bb1.w};
        if (p < 12) {
            ushort8v oA, oB;
#pragma unroll
            for (int f = 0; f < 8; ++f) {
                oA[f] = f32_to_bf16(fmaxf(aA[f] * da + bv[f], 0.0f));
                oB[f] = f32_to_bf16(fmaxf(aB[f] * db + bv[f], 0.0f));
            }
            *(ushort8v*)(&tile[tsel][j0][pe8]) = oA;
            *(ushort8v*)(&tile[tsel][j0 + 1][pe8]) = oB;
        }
    }
    __syncthreads();
    if (!active) return;

    short8 bfrag[9];
    const short8* Wz8 = (const short8*)Wz;
#pragma unroll
    for (int f = 0; f < 9; f++) bfrag[f] = Wz8[(half * 9 + f) * 64 + lane];

    const unsigned short* tp = &tile[tsel][0][0];
    short8 a[3];
#pragma unroll
    for (int kb = 0; kb < 3; kb++)
        a[kb] = *(const short8*)(tp + mrow * 104 + quad * 8 + kb * 32);
    int n0 = tt * 16;
    float dscale[4];
#pragma unroll
    for (int r = 0; r < 4; r++) dscale[r] = dinv[n0 + quad * 4 + r];
    unsigned char* orow = Out + (size_t)n0 * HID;
#pragma unroll
    for (int ntl = 0; ntl < 3; ntl++) {
        int nt = half * 3 + ntl;
        floatx4 c = {0.0f, 0.0f, 0.0f, 0.0f};
        c = __builtin_amdgcn_mfma_f32_16x16x32_bf16(a[0], bfrag[ntl * 3 + 0], c, 0, 0, 0);
        c = __builtin_amdgcn_mfma_f32_16x16x32_bf16(a[1], bfrag[ntl * 3 + 1], c, 0, 0, 0);
        c = __builtin_amdgcn_mfma_f32_16x16x32_bf16(a[2], bfrag[ntl * 3 + 2], c, 0, 0, 0);
#pragma unroll
        for (int r = 0; r < 4; r++)
            orow[(size_t)(quad * 4 + r) * HID + nt * 16 + mrow] =
                f32_to_fp8(c[r] * dscale[r]);
    }
}

// ------------------------------------------------- fused gather + pool ------
// Wide fp8 gather of 8 rows/wave (pad-4 CSR, 2-deep prefetch); stage f32 in
// per-wave LDS; then a BLOCK-level run-length pool flushing into one of
// NSPLIT psum copies (blockIdx&7) -> 8x fewer same-line atomic collisions.
__global__ __launch_bounds__(256) void gather_pool(
    const unsigned char* __restrict__ h8, const int* __restrict__ rowptr,
    const unsigned short* __restrict__ csr, const float* __restrict__ dinv,
    const float* __restrict__ bias, const int* __restrict__ batch,
    float* __restrict__ psum, float* __restrict__ pcnt, int Ntiles8, int N) {
    __shared__ float stage[4][8][96];  // 12 KB, per-wave region
    int wv = threadIdx.x >> 6;
    int lane = threadIdx.x & 63;
    int tt = blockIdx.x * 4 + wv;
    bool active = tt < Ntiles8;
    int g = lane >> 4;
    int p = lane & 15;
    int pe = (p < 12) ? p : 11;
    int pe8 = pe * 8;

    if (active) {
        int TAIL = rowptr[N];
        int n0 = tt * 8;
        int na = n0 + g * 2;
        int r0 = rowptr[na], r1 = rowptr[na + 1], r2 = rowptr[na + 2];
        float da = dinv[na], db = dinv[na + 1];
        float aA[8], aB[8];
        uint2v sva = *(const uint2v*)(h8 + (size_t)na * HID + pe8);
        uint2v svb = *(const uint2v*)(h8 + (size_t)(na + 1) * HID + pe8);
        fp8x8_decode(sva, aA);
        fp8x8_decode(svb, aB);
        int it2 = (r2 - r0 + 15) >> 4;
        int o = __shfl_xor(it2, 16, 64);
        it2 = it2 > o ? it2 : o;
        o = __shfl_xor(it2, 32, 64);
        it2 = it2 > o ? it2 : o;
        gather_core4(h8, csr, r0, r1, r2, TAIL, it2, pe8, aA, aB);
        float4 bb0 = *(const float4*)(bias + pe8);
        float4 bb1 = *(const float4*)(bias + pe8 + 4);
        float bv[8] = {bb0.x, bb0.y, bb0.z, bb0.w, bb1.x, bb1.y, bb1.z, bb1.w};
        if (p < 12) {  // last layer: no ReLU
            floatx4 oa0 = {aA[0] * da + bv[0], aA[1] * da + bv[1],
                           aA[2] * da + bv[2], aA[3] * da + bv[3]};
            floatx4 oa1 = {aA[4] * da + bv[4], aA[5] * da + bv[5],
                           aA[6] * da + bv[6], aA[7] * da + bv[7]};
            floatx4 ob0 = {aB[0] * db + bv[0], aB[1] * db + bv[1],
                           aB[2] * db + bv[2], aB[3] * db + bv[3]};
            floatx4 ob1 = {aB[4] * db + bv[4], aB[5] * db + bv[5],
                           aB[6] * db + bv[6], aB[7] * db + bv[7]};
            *(floatx4*)(&stage[wv][g * 2][pe8]) = oa0;
            *(floatx4*)(&stage[wv][g * 2][pe8 + 4]) = oa1;
            *(floatx4*)(&stage[wv][g * 2 + 1][pe8]) = ob0;
            *(floatx4*)(&stage[wv][g * 2 + 1][pe8 + 4]) = ob1;
        }
    }
    __syncthreads();

    // ---- block-level run-length pool over 32 rows (batch is sorted) ----
    int t = threadIdx.x;
    if (t < 96) {
        float* pbase = psum + (size_t)(blockIdx.x & (NSPLIT - 1)) * (NGRAPHS * HID);
        float* pcbase = pcnt + (size_t)(blockIdx.x & (NSPLIT - 1)) * NGRAPHS;
        int n0b = blockIdx.x * 32;
        int limit = N - n0b;
        if (limit > 32) limit = 32;
        int g_cur = batch[n0b];
        float s = 0.0f;
        int cnt = 0;
        for (int j = 0; j < limit; ++j) {
            int gb = batch[n0b + j];
            if (gb != g_cur) {  // uniform across threads (scalar batch value)
                atomicAdd(&pbase[g_cur * HID + t], s);
                if (t == 0) atomicAdd(&pcbase[g_cur], (float)cnt);
                s = 0.0f;
                cnt = 0;
                g_cur = gb;
            }
            s += stage[j >> 3][j & 7][t];
            cnt++;
        }
        atomicAdd(&pbase[g_cur * HID + t], s);
        if (t == 0) atomicAdd(&pcbase[g_cur], (float)cnt);
    }
}

// ---------------------------------------------------------------- head ------
// Pre-reduce the NSPLIT psum/pcnt copies through LDS, then the dense head.
__global__ __launch_bounds__(640) void final_kernel(
    const float* __restrict__ sums, const float* __restrict__ cnts,
    const float* __restrict__ Wlin, const float* __restrict__ blin,
    float* __restrict__ out) {
    __shared__ float rs[NGRAPHS * HID];  // 24 KB
    __shared__ float rc[NGRAPHS];
    int t = threadIdx.x;
    for (int i = t; i < NGRAPHS * HID; i += 640) {
        float s = 0.0f;
#pragma unroll
        for (int k = 0; k < NSPLIT; ++k) s += sums[(size_t)k * NGRAPHS * HID + i];
        rs[i] = s;
    }
    if (t < NGRAPHS) {
        float s = 0.0f;
#pragma unroll
        for (int k = 0; k < NSPLIT; ++k) s += cnts[(size_t)k * NGRAPHS + t];
        rc[t] = s;
    }
    __syncthreads();
    if (t >= NGRAPHS * 10) return;
    int g = t / 10;
    int c = t % 10;
    float denom = fmaxf(rc[g], 1.0f);
    float acc = blin[c];
#pragma unroll
    for (int f = 0; f < HID; f++)
        acc += (rs[g * HID + f] / denom) * Wlin[f * 10 + c];
    out[t] = acc;
}

// ---------------------------------------------------------------- launch ----
extern "C" void kernel_launch(void* const* d_in, const int* in_sizes, int n_in,
                              void* d_out, int out_size, void* d_ws,
                              size_t ws_size, hipStream_t stream) {
    const float* x = (const float*)d_in[0];
    const int* edge = (const int*)d_in[1];
    const int* batch = (const int*)d_in[2];
    const float* W[3] = {(const float*)d_in[3], (const float*)d_in[5],
                         (const float*)d_in[7]};
    const float* B[3] = {(const float*)d_in[4], (const float*)d_in[6],
                         (const float*)d_in[8]};
    const float* Wlin = (const float*)d_in[9];
    const float* blin = (const float*)d_in[10];
    float* out = (float*)d_out;

    int N = in_sizes[0] / HID;  // 50000
    int E = in_sizes[1] / 2;    // 800000
    const int* src = edge;
    const int* dst = edge + E;
    int NB = (N + 255) / 256;   // 196

    char* ws = (char*)d_ws;
    size_t off = 0;
    auto alloc = [&](size_t bytes) {
        void* p = ws + off;
        off += (bytes + 255) & ~(size_t)255;
        return p;
    };
    int* deg = (int*)alloc((size_t)N * 4);
    float* dinv = (float*)alloc((size_t)N * 4);
    int* rowptr = (int*)alloc(((size_t)N + 1) * 4);
    int* cursor = (int*)alloc((size_t)N * 4);
    int* blocksum = (int*)alloc((size_t)NB * 4);
    size_t csr_cap = (size_t)E + 4 * (size_t)N;  // pad-4
    unsigned short* csr_src = (unsigned short*)alloc(csr_cap * 2 + 64);
    unsigned short* Wz = (unsigned short*)alloc(3 * HID * HID * 2);
    unsigned char* bufA = (unsigned char*)alloc((size_t)NROWS * HID);  // fp8
    unsigned char* bufB = (unsigned char*)alloc((size_t)NROWS * HID);  // fp8
    float* psum = (float*)alloc((size_t)NSPLIT * (NGRAPHS * HID + NGRAPHS) * 4);
    float* pcnt = psum + (size_t)NSPLIT * NGRAPHS * HID;

    // --- CSR build + weight prep ---
    hipMemsetAsync(csr_src, 0xC3, csr_cap * 2, stream);  // pads -> sentinel row
    init_kernel<<<NB + 3, 256, 0, stream>>>(deg, psum, bufA, bufB, N, NB,
                                            W[0], W[1], W[2], Wz);
    deg_kernel<<<(E / 4 + 255) / 256, 256, 0, stream>>>(dst, deg, E);
    scan_phaseA<<<NB, 256, 0, stream>>>(deg, dinv, blocksum, N);
    scan_phaseC<<<NB, 256, 0, stream>>>(deg, blocksum, rowptr, cursor, N, NB);
    csr_fill<<<(E / 8 + 255) / 256, 256, 0, stream>>>(src, dst, cursor, csr_src, E);

    int Mtiles = (N + 15) / 16;           // 3125
    int grid2 = (Mtiles + 1) / 2;         // 1563 (2 tiles/block)
    int Ntiles8 = (N + 7) / 8;            // 6250
    int gridp = (Ntiles8 + 3) / 4;        // 1563

    gemm0_f32<<<grid2, 256, 0, stream>>>(x, Wz, dinv, bufA, Mtiles);
    fused_gather_gemm<<<grid2, 256, 0, stream>>>(
        bufA, rowptr, csr_src, dinv, B[0], Wz + 1 * HID * HID, bufB, Mtiles, N);
    fused_gather_gemm<<<grid2, 256, 0, stream>>>(
        bufB, rowptr, csr_src, dinv, B[1], Wz + 2 * HID * HID, bufA, Mtiles, N);
    gather_pool<<<gridp, 256, 0, stream>>>(bufA, rowptr, csr_src, dinv, B[2],
                                           batch, psum, pcnt, Ntiles8, N);
    final_kernel<<<1, 640, 0, stream>>>(psum, pcnt, Wlin, blin, out);
}